// Round 8
// baseline (133.045 us; speedup 1.0000x reference)
//
#include <hip/hip_runtime.h>

#define SEQ 4096
#define DIM 1024
#define MD 64
#define TOPK 16
#define WPB 2                 // waves per block
#define RPW 4                 // rows per wave (4 chains), staged 2-at-a-time
#define RPB (WPB * RPW)       // 8 rows per block; LDS = 2 staging rows/wave = 16 KB/block

typedef float nfloat4 __attribute__((ext_vector_type(4)));  // native vec for nt store

// R12 (resubmit; previous round was a container-acquisition failure, kernel
// never ran): 4 chains/wave at R9's 20-waves/CU occupancy.
// LDS holds only 2 staging rows per wave (8 KB): stage rows 0-1 -> gather
// s0,s1 -> OVERWRITE with rows 2-3 (per-wave DS ops are program-ordered, so
// the WAR on the staging buffer is safe) -> gather s2,s3. One 4-row
// interleaved mid-section then amortizes the serial ballot chain 4x
// (~400 -> ~230 cy/row) and pipelines the Hadamards' dependent shuffle
// stages 4-wide. Epilogue reloads x linearly (L3-resident second touch,
// exact: out = x + sg*w) instead of an LDS readback, keeping VGPRs low
// through the mid-section (R8 lesson: don't hold x in regs across it).
// 80 chains/CU vs R9's 40 at identical LDS/occupancy.
__global__ __launch_bounds__(WPB * 64) void csa_kernel(
    const float* __restrict__ x,
    const float* __restrict__ gates,
    const float* __restrict__ alpha,
    const float* __restrict__ tau,
    const float* __restrict__ signs,
    const int*   __restrict__ perm,
    const int*   __restrict__ inv_perm,
    const int*   __restrict__ target_idx,
    float*       __restrict__ out)
{
    __shared__ float y[WPB * 2][DIM];                 // 2 staging rows per wave

    const int lane = threadIdx.x & 63;
    const int wv   = threadIdx.x >> 6;
    const int r0   = (blockIdx.x * WPB + wv) * RPW;   // rows r0 .. r0+3
    const int b    = r0 >> 12;                        // SEQ = 4096; quad shares b

    float* y0 = y[wv * 2 + 0];
    float* y1 = y[wv * 2 + 1];

    // ---- Hoisted perm gather indices (L1-hot 4 KB, shared by all 4 rows)
    int pk[16];
    #pragma unroll
    for (int k = 0; k < 16; ++k) pk[k] = perm[lane + 64 * k];

    // ---- Stage A: rows 0,1 -> LDS (y = x*signs)
    #pragma unroll
    for (int c = 0; c < 4; ++c) {
        const float4 sg = ((const float4*)signs)[c * 64 + lane];
        const float4 xa = ((const float4*)(x + (size_t)(r0 + 0) * DIM))[c * 64 + lane];
        const float4 xb = ((const float4*)(x + (size_t)(r0 + 1) * DIM))[c * 64 + lane];
        float4 a, bq;
        a.x  = xa.x * sg.x; a.y  = xa.y * sg.y; a.z  = xa.z * sg.z; a.w  = xa.w * sg.w;
        bq.x = xb.x * sg.x; bq.y = xb.y * sg.y; bq.z = xb.z * sg.z; bq.w = xb.w * sg.w;
        ((float4*)y0)[c * 64 + lane] = a;
        ((float4*)y1)[c * 64 + lane] = bq;
    }

    // ---- Issue rows 2,3 global loads NOW; latency hides under gather A
    float4 xc[4], xd[4];
    #pragma unroll
    for (int c = 0; c < 4; ++c) {
        xc[c] = ((const float4*)(x + (size_t)(r0 + 2) * DIM))[c * 64 + lane];
        xd[c] = ((const float4*)(x + (size_t)(r0 + 3) * DIM))[c * 64 + lane];
    }

    // ---- Gather A: fold rows 0,1 (element pk[k] has bin == lane)
    float s0 = 0.f, s1 = 0.f;
    #pragma unroll
    for (int k = 0; k < 16; ++k) {
        s0 += y0[pk[k]];                              // random ds_read_b32
        s1 += y1[pk[k]];
    }

    // ---- Stage B: rows 2,3 overwrite the staging buffer (program-order WAR)
    #pragma unroll
    for (int c = 0; c < 4; ++c) {
        const float4 sg = ((const float4*)signs)[c * 64 + lane];  // L1-hot
        float4 a, bq;
        a.x  = xc[c].x * sg.x; a.y  = xc[c].y * sg.y;
        a.z  = xc[c].z * sg.z; a.w  = xc[c].w * sg.w;
        bq.x = xd[c].x * sg.x; bq.y = xd[c].y * sg.y;
        bq.z = xd[c].z * sg.z; bq.w = xd[c].w * sg.w;
        ((float4*)y0)[c * 64 + lane] = a;
        ((float4*)y1)[c * 64 + lane] = bq;
    }

    // ---- Gather B: fold rows 2,3
    float s2 = 0.f, s3 = 0.f;
    #pragma unroll
    for (int k = 0; k < 16; ++k) {
        s2 += y0[pk[k]];
        s3 += y1[pk[k]];
    }

    // ---- Phase 3a: 64-pt Hadamard, 4 chains interleaved
    float v0 = s0, v1 = s1, v2 = s2, v3 = s3;
    #pragma unroll
    for (int bit = 1; bit < MD; bit <<= 1) {
        const float o0 = __shfl_xor(v0, bit, 64);
        const float o1 = __shfl_xor(v1, bit, 64);
        const float o2 = __shfl_xor(v2, bit, 64);
        const float o3 = __shfl_xor(v3, bit, 64);
        v0 = (lane & bit) ? (o0 - v0) : (v0 + o0);
        v1 = (lane & bit) ? (o1 - v1) : (v1 + o1);
        v2 = (lane & bit) ? (o2 - v2) : (v2 + o2);
        v3 = (lane & bit) ? (o3 - v3) : (v3 + o3);
    }

    const int   ti   = target_idx[0];                 // NT == 1
    const float gate = gates[(b + ti) * MD + lane];
    const float tauv = fabsf(tau[b + ti]);
    const float al   = alpha[b + ti];

    const float g0 = gate * v0 * 0.03125f;            // 1024^-0.5
    const float g1 = gate * v1 * 0.03125f;
    const float g2 = gate * v2 * 0.03125f;
    const float g3 = gate * v3 * 0.03125f;
    const float ag0 = fabsf(g0), ag1 = fabsf(g1), ag2 = fabsf(g2), ag3 = fabsf(g3);

    // ---- Phase 3b: exact top-16 via bitwise binary search, 4 rows per
    // serial iteration (amortized); ties -> lowest lane (matches lax.top_k)
    const unsigned ka0 = __float_as_uint(ag0);
    const unsigned ka1 = __float_as_uint(ag1);
    const unsigned ka2 = __float_as_uint(ag2);
    const unsigned ka3 = __float_as_uint(ag3);
    unsigned T0 = 0u, T1 = 0u, T2 = 0u, T3 = 0u;
    #pragma unroll
    for (int bit = 30; bit >= 0; --bit) {
        const unsigned c0 = T0 | (1u << bit);
        const unsigned c1 = T1 | (1u << bit);
        const unsigned c2 = T2 | (1u << bit);
        const unsigned c3 = T3 | (1u << bit);
        if (__popcll(__ballot(ka0 >= c0)) >= TOPK) T0 = c0;
        if (__popcll(__ballot(ka1 >= c1)) >= TOPK) T1 = c1;
        if (__popcll(__ballot(ka2 >= c2)) >= TOPK) T2 = c2;
        if (__popcll(__ballot(ka3 >= c3)) >= TOPK) T3 = c3;
    }
    const unsigned long long lm = (1ull << lane) - 1ull;
    const int ngt0 = __popcll(__ballot(ka0 > T0));
    const int ngt1 = __popcll(__ballot(ka1 > T1));
    const int ngt2 = __popcll(__ballot(ka2 > T2));
    const int ngt3 = __popcll(__ballot(ka3 > T3));
    const int er0 = __popcll(__ballot(ka0 == T0) & lm);
    const int er1 = __popcll(__ballot(ka1 == T1) & lm);
    const int er2 = __popcll(__ballot(ka2 == T2) & lm);
    const int er3 = __popcll(__ballot(ka3 == T3) & lm);
    const bool k0 = (ka0 > T0) || ((ka0 == T0) && (er0 < TOPK - ngt0));
    const bool k1 = (ka1 > T1) || ((ka1 == T1) && (er1 < TOPK - ngt1));
    const bool k2 = (ka2 > T2) || ((ka2 == T2) && (er2 < TOPK - ngt2));
    const bool k3 = (ka3 > T3) || ((ka3 == T3) && (er3 < TOPK - ngt3));

    float zs0 = (k0 && ag0 >= tauv) ? al * g0 : 0.f;
    float zs1 = (k1 && ag1 >= tauv) ? al * g1 : 0.f;
    float zs2 = (k2 && ag2 >= tauv) ? al * g2 : 0.f;
    float zs3 = (k3 && ag3 >= tauv) ? al * g3 : 0.f;

    // ---- Phase 3c: second 64-pt Hadamard, 4 chains
    #pragma unroll
    for (int bit = 1; bit < MD; bit <<= 1) {
        const float o0 = __shfl_xor(zs0, bit, 64);
        const float o1 = __shfl_xor(zs1, bit, 64);
        const float o2 = __shfl_xor(zs2, bit, 64);
        const float o3 = __shfl_xor(zs3, bit, 64);
        zs0 = (lane & bit) ? (o0 - zs0) : (zs0 + o0);
        zs1 = (lane & bit) ? (o1 - zs1) : (zs1 + o1);
        zs2 = (lane & bit) ? (o2 - zs2) : (zs2 + o2);
        zs3 = (lane & bit) ? (o3 - zs3) : (zs3 + o3);
    }
    const float w0 = zs0 * 0.03125f;                  // lane L holds w_r[bin == L]
    const float w1 = zs1 * 0.03125f;
    const float w2 = zs2 * 0.03125f;
    const float w3 = zs3 * 0.03125f;

    // ---- Phase 4: out_r = x_r + signs * w_r[bin]; x reloaded linearly
    // (L2/L3-hot second touch; exact — no LDS readback needed)
    #pragma unroll
    for (int c = 0; c < 4; ++c) {
        const int4   ip = ((const int4*)inv_perm)[c * 64 + lane];   // L1-hot
        const float4 sg = ((const float4*)signs)[c * 64 + lane];
        const float4 xr0 = ((const float4*)(x + (size_t)(r0 + 0) * DIM))[c * 64 + lane];
        const float4 xr1 = ((const float4*)(x + (size_t)(r0 + 1) * DIM))[c * 64 + lane];
        const float4 xr2 = ((const float4*)(x + (size_t)(r0 + 2) * DIM))[c * 64 + lane];
        const float4 xr3 = ((const float4*)(x + (size_t)(r0 + 3) * DIM))[c * 64 + lane];
        const int b0 = ip.x & 63, b1 = ip.y & 63, b2 = ip.z & 63, b3 = ip.w & 63;

        nfloat4 o0, o1, o2, o3;
        o0.x = xr0.x + sg.x * __shfl(w0, b0, 64);
        o0.y = xr0.y + sg.y * __shfl(w0, b1, 64);
        o0.z = xr0.z + sg.z * __shfl(w0, b2, 64);
        o0.w = xr0.w + sg.w * __shfl(w0, b3, 64);
        o1.x = xr1.x + sg.x * __shfl(w1, b0, 64);
        o1.y = xr1.y + sg.y * __shfl(w1, b1, 64);
        o1.z = xr1.z + sg.z * __shfl(w1, b2, 64);
        o1.w = xr1.w + sg.w * __shfl(w1, b3, 64);
        o2.x = xr2.x + sg.x * __shfl(w2, b0, 64);
        o2.y = xr2.y + sg.y * __shfl(w2, b1, 64);
        o2.z = xr2.z + sg.z * __shfl(w2, b2, 64);
        o2.w = xr2.w + sg.w * __shfl(w2, b3, 64);
        o3.x = xr3.x + sg.x * __shfl(w3, b0, 64);
        o3.y = xr3.y + sg.y * __shfl(w3, b1, 64);
        o3.z = xr3.z + sg.z * __shfl(w3, b2, 64);
        o3.w = xr3.w + sg.w * __shfl(w3, b3, 64);

        __builtin_nontemporal_store(o0, &((nfloat4*)(out + (size_t)(r0 + 0) * DIM))[c * 64 + lane]);
        __builtin_nontemporal_store(o1, &((nfloat4*)(out + (size_t)(r0 + 1) * DIM))[c * 64 + lane]);
        __builtin_nontemporal_store(o2, &((nfloat4*)(out + (size_t)(r0 + 2) * DIM))[c * 64 + lane]);
        __builtin_nontemporal_store(o3, &((nfloat4*)(out + (size_t)(r0 + 3) * DIM))[c * 64 + lane]);
    }
}

extern "C" void kernel_launch(void* const* d_in, const int* in_sizes, int n_in,
                              void* d_out, int out_size, void* d_ws, size_t ws_size,
                              hipStream_t stream) {
    const float* x        = (const float*)d_in[0];
    const float* gates    = (const float*)d_in[1];
    const float* alpha    = (const float*)d_in[2];
    const float* tau      = (const float*)d_in[3];
    const float* signs    = (const float*)d_in[4];
    const int*   perm     = (const int*)d_in[5];
    const int*   inv_perm = (const int*)d_in[6];
    const int*   tgt      = (const int*)d_in[7];
    float*       out      = (float*)d_out;

    const int rows = 4 * SEQ;                         // BSZ * SEQ = 16384
    csa_kernel<<<rows / RPB, WPB * 64, 0, stream>>>(x, gates, alpha, tau, signs,
                                                    perm, inv_perm, tgt, out);
}

// Round 9
// 128.294 us; speedup vs baseline: 1.0370x; 1.0370x over previous
//
#include <hip/hip_runtime.h>

#define SEQ 4096
#define DIM 1024
#define MD 64
#define TOPK 16
#define WPB 2                 // waves per block
#define RPW 2                 // rows per wave (ILP: two independent chains)
#define RPB (WPB * RPW)       // 4 rows per block, 16 KB LDS

typedef float nfloat4 __attribute__((ext_vector_type(4)));  // native vec for nt store

// R13 = R9 + global_load_lds staging (raw x) + deferred signs.
// R12's counters: doubling waves didn't help (36.5% occ ~= R10's 17.6% speed
// after removing its +32MB fetch) -> R9's 20 waves x 2 chains is the LDS-capped
// optimum (epilogue readback needs the full 4KB row resident: 160/8 = 20).
// Remaining lever: the staging round-trip. Phase 1 was global->VGPR->mul->
// ds_write (16 VMEM interlocked with 16 DS + 16 VALU, +32 transient VGPRs).
// Now: 8 x global_load_lds DMA (16B/lane, wave-uniform LDS base + lane*16 --
// our layout is exactly linear), one vmcnt(0) before the gather. Signs are
// deferred: gather does s += signs[pk]*x_lds[pk] (fmac; VALU is idle), and
// the epilogue is out = x_lds + sg*w[bin] (no double multiply). Table loads
// (pk, sgk, gates/tau/alpha) issue under the DMA latency.
__device__ __forceinline__ void gload_lds16(float* lds_dst, const float* gsrc) {
    __builtin_amdgcn_global_load_lds(
        (const __attribute__((address_space(1))) void*)gsrc,
        (__attribute__((address_space(3))) void*)lds_dst,
        16, 0, 0);           // 16B per lane; dest = uniform base + lane*16
}

__global__ __launch_bounds__(WPB * 64) void csa_kernel(
    const float* __restrict__ x,
    const float* __restrict__ gates,
    const float* __restrict__ alpha,
    const float* __restrict__ tau,
    const float* __restrict__ signs,
    const int*   __restrict__ perm,
    const int*   __restrict__ inv_perm,
    const int*   __restrict__ target_idx,
    float*       __restrict__ out)
{
    __shared__ float y[RPB][DIM];                     // raw x staging

    const int lane = threadIdx.x & 63;
    const int wv   = threadIdx.x >> 6;
    const int r0   = (blockIdx.x * WPB + wv) * RPW;   // first of 2 rows (even)
    const int b    = r0 >> 12;                        // SEQ = 4096; pair shares b

    float* y0 = y[wv * RPW + 0];
    float* y1 = y[wv * RPW + 1];

    // ---- Phase 1: async DMA raw x -> LDS (wave-private rows, linear layout)
    const float* xr0 = x + (size_t)(r0 + 0) * DIM;
    const float* xr1 = x + (size_t)(r0 + 1) * DIM;
    #pragma unroll
    for (int c = 0; c < 4; ++c) {
        gload_lds16(y0 + c * 256, xr0 + c * 256 + lane * 4);
        gload_lds16(y1 + c * 256, xr1 + c * 256 + lane * 4);
    }

    // ---- Overlapped with DMA: gather tables + row-uniform params
    int   pk[16];
    float sgk[16];
    #pragma unroll
    for (int k = 0; k < 16; ++k) pk[k]  = perm[lane + 64 * k];   // L1-hot 4 KB
    #pragma unroll
    for (int k = 0; k < 16; ++k) sgk[k] = signs[pk[k]];          // L1-hot 4 KB
    const int   ti   = target_idx[0];                 // NT == 1
    const float gate = gates[(b + ti) * MD + lane];
    const float tauv = fabsf(tau[b + ti]);
    const float al   = alpha[b + ti];

    // ---- Drain DMA (and table loads) before touching the staged rows
    asm volatile("s_waitcnt vmcnt(0)" ::: "memory");

    // ---- Phase 2: fold 1024 -> 64 bins with deferred signs
    // (element pk[k] has bin == lane)
    float s0 = 0.f, s1 = 0.f;
    #pragma unroll
    for (int k = 0; k < 16; ++k) {
        const float a  = y0[pk[k]];                   // random ds_read_b32
        const float bb = y1[pk[k]];
        s0 = fmaf(sgk[k], a,  s0);
        s1 = fmaf(sgk[k], bb, s1);
    }

    // ---- Phase 3a: 64-pt Hadamard, both rows interleaved
    float v0 = s0, v1 = s1;
    #pragma unroll
    for (int bit = 1; bit < MD; bit <<= 1) {
        const float o0 = __shfl_xor(v0, bit, 64);
        const float o1 = __shfl_xor(v1, bit, 64);
        v0 = (lane & bit) ? (o0 - v0) : (v0 + o0);
        v1 = (lane & bit) ? (o1 - v1) : (v1 + o1);
    }

    const float g0 = gate * v0 * 0.03125f;            // 1024^-0.5
    const float g1 = gate * v1 * 0.03125f;
    const float ag0 = fabsf(g0), ag1 = fabsf(g1);

    // ---- Phase 3b: exact top-16 via bitwise binary search (2 chains);
    // ties -> lowest lane (matches jax.lax.top_k)
    const unsigned ka0 = __float_as_uint(ag0);
    const unsigned ka1 = __float_as_uint(ag1);
    unsigned T0 = 0u, T1 = 0u;
    #pragma unroll
    for (int bit = 30; bit >= 0; --bit) {
        const unsigned c0 = T0 | (1u << bit);
        const unsigned c1 = T1 | (1u << bit);
        if (__popcll(__ballot(ka0 >= c0)) >= TOPK) T0 = c0;
        if (__popcll(__ballot(ka1 >= c1)) >= TOPK) T1 = c1;
    }
    const int ngt0 = __popcll(__ballot(ka0 > T0));
    const int ngt1 = __popcll(__ballot(ka1 > T1));
    const unsigned long long lm = (1ull << lane) - 1ull;
    const int er0 = __popcll(__ballot(ka0 == T0) & lm);
    const int er1 = __popcll(__ballot(ka1 == T1) & lm);
    const bool k0 = (ka0 > T0) || ((ka0 == T0) && (er0 < TOPK - ngt0));
    const bool k1 = (ka1 > T1) || ((ka1 == T1) && (er1 < TOPK - ngt1));

    float zs0 = (k0 && ag0 >= tauv) ? al * g0 : 0.f;
    float zs1 = (k1 && ag1 >= tauv) ? al * g1 : 0.f;

    // ---- Phase 3c: second 64-pt Hadamard, interleaved
    #pragma unroll
    for (int bit = 1; bit < MD; bit <<= 1) {
        const float o0 = __shfl_xor(zs0, bit, 64);
        const float o1 = __shfl_xor(zs1, bit, 64);
        zs0 = (lane & bit) ? (o0 - zs0) : (zs0 + o0);
        zs1 = (lane & bit) ? (o1 - zs1) : (zs1 + o1);
    }
    const float w0 = zs0 * 0.03125f;                  // lane L holds w[bin == L]
    const float w1 = zs1 * 0.03125f;

    // ---- Phase 4: out = x (linear LDS readback, raw) + sg * bpermute(w)
    nfloat4* orow0 = (nfloat4*)(out + (size_t)(r0 + 0) * DIM);
    nfloat4* orow1 = (nfloat4*)(out + (size_t)(r0 + 1) * DIM);
    #pragma unroll
    for (int c = 0; c < 4; ++c) {
        const int4   ip = ((const int4*)inv_perm)[c * 64 + lane];   // L1-hot
        const float4 sg = ((const float4*)signs)[c * 64 + lane];
        const float4 t0 = ((const float4*)y0)[c * 64 + lane];       // ds_read_b128
        const float4 t1 = ((const float4*)y1)[c * 64 + lane];
        const float wx0 = __shfl(w0, ip.x & 63, 64);  // ds_bpermute, no conflicts
        const float wy0 = __shfl(w0, ip.y & 63, 64);
        const float wz0 = __shfl(w0, ip.z & 63, 64);
        const float ww0 = __shfl(w0, ip.w & 63, 64);
        const float wx1 = __shfl(w1, ip.x & 63, 64);
        const float wy1 = __shfl(w1, ip.y & 63, 64);
        const float wz1 = __shfl(w1, ip.z & 63, 64);
        const float ww1 = __shfl(w1, ip.w & 63, 64);
        nfloat4 o0, o1;
        o0.x = t0.x + sg.x * wx0;
        o0.y = t0.y + sg.y * wy0;
        o0.z = t0.z + sg.z * wz0;
        o0.w = t0.w + sg.w * ww0;
        o1.x = t1.x + sg.x * wx1;
        o1.y = t1.y + sg.y * wy1;
        o1.z = t1.z + sg.z * wz1;
        o1.w = t1.w + sg.w * ww1;
        __builtin_nontemporal_store(o0, &orow0[c * 64 + lane]);
        __builtin_nontemporal_store(o1, &orow1[c * 64 + lane]);
    }
}

extern "C" void kernel_launch(void* const* d_in, const int* in_sizes, int n_in,
                              void* d_out, int out_size, void* d_ws, size_t ws_size,
                              hipStream_t stream) {
    const float* x        = (const float*)d_in[0];
    const float* gates    = (const float*)d_in[1];
    const float* alpha    = (const float*)d_in[2];
    const float* tau      = (const float*)d_in[3];
    const float* signs    = (const float*)d_in[4];
    const int*   perm     = (const int*)d_in[5];
    const int*   inv_perm = (const int*)d_in[6];
    const int*   tgt      = (const int*)d_in[7];
    float*       out      = (float*)d_out;

    const int rows = 4 * SEQ;                         // BSZ * SEQ = 16384
    csa_kernel<<<rows / RPB, WPB * 64, 0, stream>>>(x, gates, alpha, tau, signs,
                                                    perm, inv_perm, tgt, out);
}

// Round 10
// 123.256 us; speedup vs baseline: 1.0794x; 1.0409x over previous
//
#include <hip/hip_runtime.h>

#define SEQ 4096
#define DIM 1024
#define MD 64
#define TOPK 16
#define WPB 2                 // waves per block
#define RPW 2                 // rows per wave (ILP: two independent chains)
#define RPB (WPB * RPW)       // 4 rows per block, 16 KB LDS

typedef float nfloat4 __attribute__((ext_vector_type(4)));  // native vec for nt store

// R14 = R9 reverted (best measured: 122.88 µs). Terminal state of the session.
// Ledger: R6 123.2 | R7b 133.4 | R8 129.2 | R9 122.9 | R10 126.8 | R11 126.0
// | R12 133.0 | R13 128.3. Seven structural variants (more TLP, more ILP,
// fewer DS ops, async DMA, pipelining) all bracket R9: 20 waves/CU x 2 chains
// with LDS staging + conflict-free bpermute epilogue is the local optimum.
// Counters (R10/R12): latency-bound, no pipe saturated; bench total dominated
// by two harness 256MB poison fills (~84 µs @ 80% HBM peak).
__global__ __launch_bounds__(WPB * 64) void csa_kernel(
    const float* __restrict__ x,
    const float* __restrict__ gates,
    const float* __restrict__ alpha,
    const float* __restrict__ tau,
    const float* __restrict__ signs,
    const int*   __restrict__ perm,
    const int*   __restrict__ inv_perm,
    const int*   __restrict__ target_idx,
    float*       __restrict__ out)
{
    __shared__ float y[RPB][DIM];

    const int lane = threadIdx.x & 63;
    const int wv   = threadIdx.x >> 6;
    const int r0   = (blockIdx.x * WPB + wv) * RPW;   // first of 2 rows (even)
    const int b    = r0 >> 12;                        // SEQ = 4096; pair shares b

    float* y0 = y[wv * RPW + 0];
    float* y1 = y[wv * RPW + 1];

    // ---- Phase 1: coalesced loads; y = x*signs -> LDS (x regs then dead).
    // Rows are wave-private: no barrier, only lgkmcnt (compiler-inserted).
    #pragma unroll
    for (int c = 0; c < 4; ++c) {
        const float4 sg = ((const float4*)signs)[c * 64 + lane];
        const float4 xa = ((const float4*)(x + (size_t)(r0 + 0) * DIM))[c * 64 + lane];
        const float4 xb = ((const float4*)(x + (size_t)(r0 + 1) * DIM))[c * 64 + lane];
        float4 a, bq;
        a.x  = xa.x * sg.x; a.y  = xa.y * sg.y; a.z  = xa.z * sg.z; a.w  = xa.w * sg.w;
        bq.x = xb.x * sg.x; bq.y = xb.y * sg.y; bq.z = xb.z * sg.z; bq.w = xb.w * sg.w;
        ((float4*)y0)[c * 64 + lane] = a;
        ((float4*)y1)[c * 64 + lane] = bq;
    }

    // ---- Phase 2: fold 1024 -> 64 bins; pure accumulate (no kept arrays).
    // Element perm[lane + 64k] has bin == lane.
    float s0 = 0.f, s1 = 0.f;
    #pragma unroll
    for (int k = 0; k < 16; ++k) {
        const int p = perm[lane + 64 * k];            // coalesced, L1-hot 4 KB
        s0 += y0[p];                                  // random ds_read_b32
        s1 += y1[p];
    }

    // ---- Phase 3a: 64-pt Hadamard, both rows interleaved
    float v0 = s0, v1 = s1;
    #pragma unroll
    for (int bit = 1; bit < MD; bit <<= 1) {
        const float o0 = __shfl_xor(v0, bit, 64);
        const float o1 = __shfl_xor(v1, bit, 64);
        v0 = (lane & bit) ? (o0 - v0) : (v0 + o0);
        v1 = (lane & bit) ? (o1 - v1) : (v1 + o1);
    }

    const int   ti   = target_idx[0];                 // NT == 1
    const float gate = gates[(b + ti) * MD + lane];
    const float tauv = fabsf(tau[b + ti]);
    const float al   = alpha[b + ti];

    const float g0 = gate * v0 * 0.03125f;            // 1024^-0.5
    const float g1 = gate * v1 * 0.03125f;
    const float ag0 = fabsf(g0), ag1 = fabsf(g1);

    // ---- Phase 3b: exact top-16 via bitwise binary search (2 chains);
    // ties -> lowest lane (matches jax.lax.top_k)
    const unsigned ka0 = __float_as_uint(ag0);
    const unsigned ka1 = __float_as_uint(ag1);
    unsigned T0 = 0u, T1 = 0u;
    #pragma unroll
    for (int bit = 30; bit >= 0; --bit) {
        const unsigned c0 = T0 | (1u << bit);
        const unsigned c1 = T1 | (1u << bit);
        if (__popcll(__ballot(ka0 >= c0)) >= TOPK) T0 = c0;
        if (__popcll(__ballot(ka1 >= c1)) >= TOPK) T1 = c1;
    }
    const int ngt0 = __popcll(__ballot(ka0 > T0));
    const int ngt1 = __popcll(__ballot(ka1 > T1));
    const unsigned long long lm = (1ull << lane) - 1ull;
    const int er0 = __popcll(__ballot(ka0 == T0) & lm);
    const int er1 = __popcll(__ballot(ka1 == T1) & lm);
    const bool k0 = (ka0 > T0) || ((ka0 == T0) && (er0 < TOPK - ngt0));
    const bool k1 = (ka1 > T1) || ((ka1 == T1) && (er1 < TOPK - ngt1));

    float zs0 = (k0 && ag0 >= tauv) ? al * g0 : 0.f;
    float zs1 = (k1 && ag1 >= tauv) ? al * g1 : 0.f;

    // ---- Phase 3c: second 64-pt Hadamard, interleaved
    #pragma unroll
    for (int bit = 1; bit < MD; bit <<= 1) {
        const float o0 = __shfl_xor(zs0, bit, 64);
        const float o1 = __shfl_xor(zs1, bit, 64);
        zs0 = (lane & bit) ? (o0 - zs0) : (zs0 + o0);
        zs1 = (lane & bit) ? (o1 - zs1) : (zs1 + o1);
    }
    const float w0 = zs0 * 0.03125f;                  // lane L holds w[bin == L]
    const float w1 = zs1 * 0.03125f;

    // ---- Phase 4: out = signs * ( y (linear LDS readback) + bpermute(w) ).
    // Zero scattered LDS ops; signs/inv_perm reloads are L1-hot (4 KB each).
    nfloat4* orow0 = (nfloat4*)(out + (size_t)(r0 + 0) * DIM);
    nfloat4* orow1 = (nfloat4*)(out + (size_t)(r0 + 1) * DIM);
    #pragma unroll
    for (int c = 0; c < 4; ++c) {
        const int4   ip = ((const int4*)inv_perm)[c * 64 + lane];
        const float4 sg = ((const float4*)signs)[c * 64 + lane];
        const float4 t0 = ((const float4*)y0)[c * 64 + lane];   // ds_read_b128
        const float4 t1 = ((const float4*)y1)[c * 64 + lane];
        const float wx0 = __shfl(w0, ip.x & 63, 64);  // ds_bpermute, no conflicts
        const float wy0 = __shfl(w0, ip.y & 63, 64);
        const float wz0 = __shfl(w0, ip.z & 63, 64);
        const float ww0 = __shfl(w0, ip.w & 63, 64);
        const float wx1 = __shfl(w1, ip.x & 63, 64);
        const float wy1 = __shfl(w1, ip.y & 63, 64);
        const float wz1 = __shfl(w1, ip.z & 63, 64);
        const float ww1 = __shfl(w1, ip.w & 63, 64);
        nfloat4 o0, o1;
        o0.x = sg.x * (t0.x + wx0);
        o0.y = sg.y * (t0.y + wy0);
        o0.z = sg.z * (t0.z + wz0);
        o0.w = sg.w * (t0.w + ww0);
        o1.x = sg.x * (t1.x + wx1);
        o1.y = sg.y * (t1.y + wy1);
        o1.z = sg.z * (t1.z + wz1);
        o1.w = sg.w * (t1.w + ww1);
        __builtin_nontemporal_store(o0, &orow0[c * 64 + lane]);
        __builtin_nontemporal_store(o1, &orow1[c * 64 + lane]);
    }
}

extern "C" void kernel_launch(void* const* d_in, const int* in_sizes, int n_in,
                              void* d_out, int out_size, void* d_ws, size_t ws_size,
                              hipStream_t stream) {
    const float* x        = (const float*)d_in[0];
    const float* gates    = (const float*)d_in[1];
    const float* alpha    = (const float*)d_in[2];
    const float* tau      = (const float*)d_in[3];
    const float* signs    = (const float*)d_in[4];
    const int*   perm     = (const int*)d_in[5];
    const int*   inv_perm = (const int*)d_in[6];
    const int*   tgt      = (const int*)d_in[7];
    float*       out      = (float*)d_out;

    const int rows = 4 * SEQ;                         // BSZ * SEQ = 16384
    csa_kernel<<<rows / RPB, WPB * 64, 0, stream>>>(x, gates, alpha, tau, signs,
                                                    perm, inv_perm, tgt, out);
}